// Round 3
// baseline (147.464 us; speedup 1.0000x reference)
//
#include <hip/hip_runtime.h>
#include <math.h>

// LITERAL transcription of the reference (no algebraic collapse) +
// runtime size-based input remapping (robust to dict vs alphabetical
// npz key ordering). Sizes: pos=1572864, tp_w0=8, tp_w1=4, lin_w0=64,
// lin_w1=16, clf_w1=384, clf_b1=32, clf_w2=64, clf_b2=2.

__global__ __launch_bounds__(256) void eq_literal(
    const float* __restrict__ pos,
    const float* __restrict__ tp_w0,
    const float* __restrict__ tp_w1,
    const float* __restrict__ lin_w0,
    const float* __restrict__ lin_w1,
    const float* __restrict__ clf_w1,
    const float* __restrict__ clf_b1,
    const float* __restrict__ clf_w2,
    const float* __restrict__ clf_b2,
    float* __restrict__ out,
    int Btot)
{
    const int b = blockIdx.x * blockDim.x + threadIdx.x;
    if (b >= Btot) return;

    const float S3     = 1.7320508075688772f;   // sqrt(3)
    const float INV_S8 = 0.35355339059327373f;  // 1/sqrt(8)
    const float INV_S4 = 0.5f;                  // 1/sqrt(4)

    const float4* p4 = (const float4*)(pos + (size_t)b * 12);
    const float4 q0 = p4[0], q1 = p4[1], q2 = p4[2];
    const float p[4][3] = {
        {q0.x, q0.y, q0.z},
        {q0.w, q1.x, q1.y},
        {q1.z, q1.w, q2.x},
        {q2.y, q2.z, q2.w}
    };

    float invv[12];
    #pragma unroll
    for (int c = 0; c < 12; ++c) invv[c] = 0.f;

    #pragma unroll
    for (int i = 0; i < 4; ++i) {
        float A0[8];
        float A1[4][3];
        #pragma unroll
        for (int v = 0; v < 8; ++v) A0[v] = 0.f;
        #pragma unroll
        for (int v = 0; v < 4; ++v) { A1[v][0] = 0.f; A1[v][1] = 0.f; A1[v][2] = 0.f; }

        #pragma unroll
        for (int kk = 0; kk < 4; ++kk) {
            if (kk == i) continue;
            // rel = p[kk] - p[i]; r = rel / ||rel||
            const float rel0 = p[kk][0] - p[i][0];
            const float rel1 = p[kk][1] - p[i][1];
            const float rel2 = p[kk][2] - p[i][2];
            const float nrm = sqrtf(rel0 * rel0 + rel1 * rel1 + rel2 * rel2);
            const float r0 = rel0 / nrm, r1 = rel1 / nrm, r2 = rel2 / nrm;
            // sh1 = sqrt(3) * r
            const float sh[3] = {S3 * r0, S3 * r1, S3 * r2};

            // m0 = ones * tp_w0 ; NormActivation: m0 *= relu(|m0|)/|m0| (0 if 0)
            float m0[8];
            #pragma unroll
            for (int u = 0; u < 8; ++u) {
                const float v = tp_w0[u];
                const float n = fabsf(v);
                const float f = (n > 0.f) ? (fmaxf(n, 0.f) / n) : 0.f;
                m0[u] = v * f;
            }
            // m1[u][m] = sh[m] * tp_w1[u] ; NormActivation over m
            float m1[4][3];
            #pragma unroll
            for (int u = 0; u < 4; ++u) {
                const float w = tp_w1[u];
                const float a = sh[0] * w, bb = sh[1] * w, cc = sh[2] * w;
                const float n = sqrtf(a * a + bb * bb + cc * cc);
                const float f = (n > 0.f) ? (fmaxf(n, 0.f) / n) : 0.f;
                m1[u][0] = a * f; m1[u][1] = bb * f; m1[u][2] = cc * f;
            }
            // h0 = (m0 @ lin_w0) / sqrt(8) ; accumulate over neighbors
            #pragma unroll
            for (int v = 0; v < 8; ++v) {
                float s = 0.f;
                #pragma unroll
                for (int u = 0; u < 8; ++u) s = fmaf(m0[u], lin_w0[u * 8 + v], s);
                A0[v] += s * INV_S8;
            }
            // h1[v][m] = (sum_u m1[u][m] lin_w1[u][v]) / sqrt(4)
            #pragma unroll
            for (int v = 0; v < 4; ++v) {
                #pragma unroll
                for (int m = 0; m < 3; ++m) {
                    float s = 0.f;
                    #pragma unroll
                    for (int u = 0; u < 4; ++u) s = fmaf(m1[u][m], lin_w1[u * 4 + v], s);
                    A1[v][m] += s * INV_S4;
                }
            }
        }
        // inv += concat(a0^2, sum_m a1^2)
        #pragma unroll
        for (int v = 0; v < 8; ++v) invv[v] += A0[v] * A0[v];
        #pragma unroll
        for (int v = 0; v < 4; ++v)
            invv[8 + v] += A1[v][0] * A1[v][0] + A1[v][1] * A1[v][1] + A1[v][2] * A1[v][2];
    }

    // hid = relu(inv @ clf_w1 + clf_b1) ; out = hid @ clf_w2 + clf_b2
    float o0 = clf_b2[0], o1 = clf_b2[1];
    #pragma unroll
    for (int k = 0; k < 32; ++k) {
        float h = clf_b1[k];
        #pragma unroll
        for (int c = 0; c < 12; ++c) h = fmaf(invv[c], clf_w1[c * 32 + k], h);
        h = fmaxf(h, 0.f);
        o0 = fmaf(h, clf_w2[k * 2 + 0], o0);
        o1 = fmaf(h, clf_w2[k * 2 + 1], o1);
    }

    float2* ov = (float2*)(out + (size_t)b * 2);
    *ov = make_float2(o0, o1);
}

extern "C" void kernel_launch(void* const* d_in, const int* in_sizes, int n_in,
                              void* d_out, int out_size, void* d_ws, size_t ws_size,
                              hipStream_t stream) {
    // Default: setup_inputs() dict order.
    int ip = 0, iw0 = 1, iw1 = 2, il0 = 3, il1 = 4, icw1 = 5, icb1 = 6, icw2 = 7, icb2 = 8;

    const bool dictOK = (n_in == 9) &&
        in_sizes[1] == 8 && in_sizes[2] == 4 && in_sizes[3] == 64 &&
        in_sizes[4] == 16 && in_sizes[5] == 384 && in_sizes[6] == 32 &&
        in_sizes[7] == 64 && in_sizes[8] == 2 && in_sizes[0] > 1000;

    if (!dictOK) {
        // Remap by (unique) sizes; the two 64s (lin_w0, clf_w2) are
        // disambiguated by position relative to clf_w1 (384): in
        // alphabetical order clf_w1 < clf_w2 < lin_w0; in dict order
        // lin_w0 < clf_w1 < clf_w2.
        int big = 0; long bigv = -1;
        for (int i = 0; i < n_in; ++i)
            if ((long)in_sizes[i] > bigv) { bigv = in_sizes[i]; big = i; }
        ip = big;
        int s64[2]; int n64 = 0;
        for (int i = 0; i < n_in; ++i) {
            if (i == ip) continue;
            switch (in_sizes[i]) {
                case 8:   iw0  = i; break;
                case 4:   iw1  = i; break;
                case 16:  il1  = i; break;
                case 384: icw1 = i; break;
                case 32:  icb1 = i; break;
                case 2:   icb2 = i; break;
                case 64:  if (n64 < 2) s64[n64++] = i; break;
                default: break;
            }
        }
        if (n64 == 2) {
            if (icw1 < s64[0]) { icw2 = s64[0]; il0 = s64[1]; }
            else               { il0  = s64[0]; icw2 = s64[1]; }
        }
    }

    const float* pos    = (const float*)d_in[ip];
    const float* tp_w0  = (const float*)d_in[iw0];
    const float* tp_w1  = (const float*)d_in[iw1];
    const float* lin_w0 = (const float*)d_in[il0];
    const float* lin_w1 = (const float*)d_in[il1];
    const float* clf_w1 = (const float*)d_in[icw1];
    const float* clf_b1 = (const float*)d_in[icb1];
    const float* clf_w2 = (const float*)d_in[icw2];
    const float* clf_b2 = (const float*)d_in[icb2];
    float* out = (float*)d_out;

    const int Btot = in_sizes[ip] / 12;
    const int grid = (Btot + 255) / 256;

    eq_literal<<<grid, 256, 0, stream>>>(pos, tp_w0, tp_w1, lin_w0, lin_w1,
                                         clf_w1, clf_b1, clf_w2, clf_b2,
                                         out, Btot);
}

// Round 7
// 75.101 us; speedup vs baseline: 1.9636x; 1.9636x over previous
//
#include <hip/hip_runtime.h>
#include <math.h>

// Collapsed form of the reference. Round-3 literal kernel passed; rounds
// 1/2/4 failed with identical error because the collapsed l=1 term
// double-counted the 1/sqrt(4): 0.75 = (sqrt(3)/2)^2 ALREADY contains it.
//   inv[b, v<8]  = 36 * h0[v]^2,   h0[v] = (tp_w0 . lin_w0[:,v])/sqrt(8)
//   inv[b, 8+v]  = 0.75 * c1[v]^2 * S_b,  c1[v] = tp_w1 . lin_w1[:,v]  (RAW dot)
//   S_b = sum_i || sum_{j!=i} normalize(p_j - p_i) ||^2
//   out[b] = b2 + sum_k relu(A[k] + S_b*D[k]) * W2[k,:]

__global__ __launch_bounds__(256) void eq_fused(
    const float* __restrict__ pos,
    const float* __restrict__ tp_w0,
    const float* __restrict__ tp_w1,
    const float* __restrict__ lin_w0,
    const float* __restrict__ lin_w1,
    const float* __restrict__ clf_w1,
    const float* __restrict__ clf_b1,
    const float* __restrict__ clf_w2,
    const float* __restrict__ clf_b2,
    float* __restrict__ out,
    int Btot)
{
    __shared__ float sA[32], sD[32], sW0[32], sW1[32], sB2[2];
    const int t = threadIdx.x;

    if (t < 32) {
        // base0[v] = 36*h0[v]^2 ; h0[v] = (tp_w0 . lin_w0[:,v]) / sqrt(8)
        float base0[8];
        #pragma unroll
        for (int v = 0; v < 8; ++v) {
            float s = 0.f;
            #pragma unroll
            for (int u = 0; u < 8; ++u) s = fmaf(tp_w0[u], lin_w0[u * 8 + v], s);
            s *= 0.35355339059327373f;   // 1/sqrt(8)
            base0[v] = 36.f * s * s;
        }
        // dirv[v] = 0.75 * c1[v]^2 ; c1[v] = RAW tp_w1 . lin_w1[:,v]
        // (the 1/sqrt(4) is inside 0.75 = (sqrt(3)/2)^2 — do NOT halve c1)
        float dirv[4];
        #pragma unroll
        for (int v = 0; v < 4; ++v) {
            float c = 0.f;
            #pragma unroll
            for (int u = 0; u < 4; ++u) c = fmaf(tp_w1[u], lin_w1[u * 4 + v], c);
            dirv[v] = 0.75f * c * c;
        }
        float A = clf_b1[t];
        #pragma unroll
        for (int v = 0; v < 8; ++v) A = fmaf(base0[v], clf_w1[v * 32 + t], A);
        float Dv = 0.f;
        #pragma unroll
        for (int v = 0; v < 4; ++v) Dv = fmaf(dirv[v], clf_w1[(8 + v) * 32 + t], Dv);
        sA[t] = A;
        sD[t] = Dv;
        sW0[t] = clf_w2[t * 2 + 0];
        sW1[t] = clf_w2[t * 2 + 1];
        if (t < 2) sB2[t] = clf_b2[t];
    }
    __syncthreads();

    const int b = blockIdx.x * blockDim.x + t;
    if (b >= Btot) return;

    const float4* p4 = (const float4*)(pos + (size_t)b * 12);
    const float4 q0 = p4[0], q1 = p4[1], q2 = p4[2];
    const float px[4] = {q0.x, q0.w, q1.z, q2.y};
    const float py[4] = {q0.y, q1.x, q1.w, q2.z};
    const float pz[4] = {q0.z, q1.y, q2.x, q2.w};

    float Rx[4] = {0.f, 0.f, 0.f, 0.f};
    float Ry[4] = {0.f, 0.f, 0.f, 0.f};
    float Rz[4] = {0.f, 0.f, 0.f, 0.f};

    #pragma unroll
    for (int i = 0; i < 4; ++i) {
        #pragma unroll
        for (int j = i + 1; j < 4; ++j) {
            float dx = px[j] - px[i];
            float dy = py[j] - py[i];
            float dz = pz[j] - pz[i];
            // exact normalize (matches the passing literal kernel's precision)
            float inv = 1.0f / sqrtf(fmaf(dx, dx, fmaf(dy, dy, dz * dz)));
            dx *= inv; dy *= inv; dz *= inv;
            Rx[i] += dx; Ry[i] += dy; Rz[i] += dz;   // normalize(p_j - p_i)
            Rx[j] -= dx; Ry[j] -= dy; Rz[j] -= dz;   // antisymmetric partner
        }
    }

    float S = 0.f;
    #pragma unroll
    for (int i = 0; i < 4; ++i)
        S += fmaf(Rx[i], Rx[i], fmaf(Ry[i], Ry[i], Rz[i] * Rz[i]));

    float o0 = sB2[0];
    float o1 = sB2[1];
    #pragma unroll
    for (int k = 0; k < 32; ++k) {
        float h = fmaxf(fmaf(S, sD[k], sA[k]), 0.f);
        o0 = fmaf(h, sW0[k], o0);
        o1 = fmaf(h, sW1[k], o1);
    }

    float2* ov = (float2*)(out + (size_t)b * 2);
    *ov = make_float2(o0, o1);
}

extern "C" void kernel_launch(void* const* d_in, const int* in_sizes, int n_in,
                              void* d_out, int out_size, void* d_ws, size_t ws_size,
                              hipStream_t stream) {
    // Dict order (verified working in round 3); size-based remap kept as a
    // harmless fallback.
    int ip = 0, iw0 = 1, iw1 = 2, il0 = 3, il1 = 4, icw1 = 5, icb1 = 6, icw2 = 7, icb2 = 8;

    const bool dictOK = (n_in == 9) &&
        in_sizes[1] == 8 && in_sizes[2] == 4 && in_sizes[3] == 64 &&
        in_sizes[4] == 16 && in_sizes[5] == 384 && in_sizes[6] == 32 &&
        in_sizes[7] == 64 && in_sizes[8] == 2 && in_sizes[0] > 1000;

    if (!dictOK) {
        int big = 0; long bigv = -1;
        for (int i = 0; i < n_in; ++i)
            if ((long)in_sizes[i] > bigv) { bigv = in_sizes[i]; big = i; }
        ip = big;
        int s64[2]; int n64 = 0;
        for (int i = 0; i < n_in; ++i) {
            if (i == ip) continue;
            switch (in_sizes[i]) {
                case 8:   iw0  = i; break;
                case 4:   iw1  = i; break;
                case 16:  il1  = i; break;
                case 384: icw1 = i; break;
                case 32:  icb1 = i; break;
                case 2:   icb2 = i; break;
                case 64:  if (n64 < 2) s64[n64++] = i; break;
                default: break;
            }
        }
        if (n64 == 2) {
            if (icw1 < s64[0]) { icw2 = s64[0]; il0 = s64[1]; }
            else               { il0  = s64[0]; icw2 = s64[1]; }
        }
    }

    const float* pos    = (const float*)d_in[ip];
    const float* tp_w0  = (const float*)d_in[iw0];
    const float* tp_w1  = (const float*)d_in[iw1];
    const float* lin_w0 = (const float*)d_in[il0];
    const float* lin_w1 = (const float*)d_in[il1];
    const float* clf_w1 = (const float*)d_in[icw1];
    const float* clf_b1 = (const float*)d_in[icb1];
    const float* clf_w2 = (const float*)d_in[icw2];
    const float* clf_b2 = (const float*)d_in[icb2];
    float* out = (float*)d_out;

    const int Btot = in_sizes[ip] / 12;
    const int grid = (Btot + 255) / 256;

    eq_fused<<<grid, 256, 0, stream>>>(pos, tp_w0, tp_w1, lin_w0, lin_w1,
                                       clf_w1, clf_b1, clf_w2, clf_b2,
                                       out, Btot);
}